// Round 13
// baseline (190.555 us; speedup 1.0000x reference)
//
#include <hip/hip_runtime.h>

typedef _Float16 f16;
typedef _Float16 f16x8 __attribute__((ext_vector_type(8)));
typedef float f32x4 __attribute__((ext_vector_type(4)));
typedef int iv2 __attribute__((ext_vector_type(2)));

#define INV_R (1.0f / 40.0f)
#define NBLK 512

// ---- FULL layout (cooperative path), bytes ----
#define F_BAR  0u            // u32[576] barrier
#define F_SELF 2304u         // u32[8] per-XCD rank counters + u32 overflow flag
#define F_B0   2368u         // f32[64] layer-0 fused bias
#define F_K    2624u         // KT copy 0 (f16, 1,141,760 elems = 2,283,520 B)
#define F_HT   2286144u      // 5 x f16[80][512]
#define F_T0   2695744u      // f16[512][4320]
#define F_T1   7119424u      // f16[512][4160]
#define F_T2   11379264u
#define F_T3   15639104u
#define F_T4   19898944u
#define F_OG   24158784u     // f32[512][64] residual (block-private)
#define NEED_FULL 24289856u
#define F_KP   24289856u     // KT copies 1..7 (7 x 2,283,520 B)
#define NEED_KTPRIV 40274496u

#define KT_ELEMS 1141760u
#define KT_BYTES 2283520u

// ---- COMPACT layout (fallback plain-launch path), bytes ----
#define C_B0  2304u
#define C_K   2560u
#define C_HTA 2286080u
#define C_HTB 2368000u
#define C_TA  2449920u
#define C_TB  6873600u
#define C_OG  11133440u

// K sub-offsets (bytes from a copy base): K0 [64][4320], K1..K3 [64][4160], K4 [16][4160]
#define K1_OFF 552960u
#define K2_OFF 1085440u
#define K3_OFF 1617920u
#define K4_OFF 2150400u

// ---- system-scope stores (write-through to coherent point) ----
__device__ __forceinline__ void st_sys_u16(void* p, unsigned v) {
  asm volatile("global_store_short %0, %1, off sc0 sc1" :: "v"(p), "v"(v) : "memory");
}
__device__ __forceinline__ void st_sys_f32(float* p, float v) {
  asm volatile("global_store_dword %0, %1, off sc0 sc1" :: "v"(p), "v"(v) : "memory");
}
__device__ __forceinline__ void st_sys_b64(void* p, iv2 v) {
  asm volatile("global_store_dwordx2 %0, %1, off sc0 sc1" :: "v"(p), "v"(v) : "memory");
}
__device__ __forceinline__ unsigned f16bits(float x) {
  union { f16 h; unsigned short s; } cv; cv.h = (f16)x; return (unsigned)cv.s;
}

// ============ fence-free hierarchical grid barrier (r11) ============
__device__ __forceinline__ unsigned bar_ld(unsigned* p) {
  return __hip_atomic_load(p, __ATOMIC_RELAXED, __HIP_MEMORY_SCOPE_AGENT);
}
__device__ void gridbar(unsigned* bar, int phase) {
  asm volatile("s_waitcnt vmcnt(0)" ::: "memory");   // drain stores
  __syncthreads();
  if (threadIdx.x == 0) {
    int bid = blockIdx.x;
    int cls = bid & 7;
    unsigned* xcnt = bar + cls * 32 + phase;
    unsigned* xrel = bar + 256 + cls * 32 + phase;
    unsigned* gcnt = bar + 512 + phase;
    unsigned* grel = bar + 544 + phase;
    __hip_atomic_fetch_add(xcnt, 1u, __ATOMIC_RELAXED, __HIP_MEMORY_SCOPE_AGENT);
    if (bid < 8) {
      while (bar_ld(xcnt) < (NBLK / 8)) __builtin_amdgcn_s_sleep(2);
      __hip_atomic_fetch_add(gcnt, 1u, __ATOMIC_RELAXED, __HIP_MEMORY_SCOPE_AGENT);
      if (bid == 0) {
        while (bar_ld(gcnt) < 8u) __builtin_amdgcn_s_sleep(2);
        __hip_atomic_store(grel, 1u, __ATOMIC_RELAXED, __HIP_MEMORY_SCOPE_AGENT);
      } else {
        while (bar_ld(grel) == 0u) __builtin_amdgcn_s_sleep(4);
      }
      __hip_atomic_store(xrel, 1u, __ATOMIC_RELAXED, __HIP_MEMORY_SCOPE_AGENT);
    } else {
      while (bar_ld(xrel) == 0u) __builtin_amdgcn_s_sleep(64);
    }
    asm volatile("" ::: "memory");
  }
  __syncthreads();
}

// ================= math helpers =================
__device__ __forceinline__ float feats0_val(int ch, int n, const float* v, const float* other) {
  if (ch == 0) return 1.0f;
  if (ch < 4) return v[n * 3 + (ch - 1)];
  return other[n * 62 + (ch - 4)];
}
__device__ __forceinline__ float atan_poly(float t) {
  float t2 = t * t;
  float p = -0.0117212f;
  p = p * t2 + 0.05265332f;
  p = p * t2 - 0.11643287f;
  p = p * t2 + 0.19354346f;
  p = p * t2 - 0.33262347f;
  p = p * t2 + 0.99997726f;
  return t * p;
}
__device__ __forceinline__ void axis_w(float g, int& i0c, int& i1c, float& w0, float& w1) {
  float c = 2.0f * g + 1.5f;
  float fl = floorf(c);
  float f = c - fl;
  int i0 = (int)fl;
  w0 = (i0 >= 0 && i0 <= 3) ? (1.0f - f) : 0.0f;
  w1 = (i0 >= -1 && i0 <= 2) ? f : 0.0f;
  i0c = min(max(i0, 0), 3);
  i1c = min(max(i0 + 1, 0), 3);
}

// ============ prep (shared small part): hT0, t0 dense tail, B0 — sc01 (cross-XCD) ============
__device__ void prep_shared(const float* __restrict__ v, const float* __restrict__ other,
                            const float* __restrict__ bf,
                            float* __restrict__ B0, f16* __restrict__ hT0,
                            f16* __restrict__ t0) {
  for (int idx = blockIdx.x * 256 + threadIdx.x; idx < 90176; idx += NBLK * 256) {
    int e = idx;
    if (e < 40960) {
      int i = e >> 9, n = e & 511;
      float val = (i < 66) ? feats0_val(i, n, v, other) : 0.0f;
      st_sys_u16(hT0 + e, f16bits(val));
      continue;
    }
    e -= 40960;
    if (e < 49152) {
      int m = e / 96, j = e % 96;
      float val = (j < 66) ? feats0_val(j, m, v, other) : 0.0f;
      st_sys_u16(t0 + (size_t)m * 4320 + 4224 + j, f16bits(val));
      continue;
    }
    e -= 49152;
    if (e < 64) st_sys_f32(&B0[e], (e < 32) ? 0.0f : bf[e - 32]);
  }
}

// ============ prep (KT): pack all 5 layer kernels into one f16 copy ============
// SYS=true: sc01 stores (shared copy, cross-XCD consumers).
// SYS=false: plain write-back stores (XCD-private copy, same-XCD consumers).
template<bool SYS>
__device__ void prep_kt(const float* __restrict__ kf, const float* __restrict__ Wf,
                        const float* __restrict__ k1, const float* __restrict__ W1,
                        const float* __restrict__ k2, const float* __restrict__ W2,
                        const float* __restrict__ k3, const float* __restrict__ W3,
                        const float* __restrict__ k4, const float* __restrict__ W4,
                        f16* __restrict__ dst, unsigned start, unsigned stride) {
  for (unsigned e = start; e < KT_ELEMS; e += stride) {
    unsigned ee = e;
    float val = 0.0f;
    if (ee < 276480u) {                      // K0: rows 0..31 conv, rows 32..63 dense
      int o = ee / 4320, k = ee % 4320;
      if (o < 32) { if (k < 4224) val = kf[o * 4224 + k]; }
      else if (k >= 4224 && k < 4290) val = Wf[(o - 32) * 66 + (k - 4224)];
    } else if (ee < 1075200u) {              // K1..K3: conv 4096 | dense 64
      unsigned f = ee - 276480u;
      int which = f / 266240, g = f % 266240;
      const float* kk = which == 0 ? k1 : (which == 1 ? k2 : k3);
      const float* WW = which == 0 ? W1 : (which == 1 ? W2 : W3);
      int o = g / 4160, k = g % 4160;
      val = (k < 4096) ? kk[o * 4096 + k] : WW[o * 64 + (k - 4096)];
    } else {                                 // K4 (6 real rows, padded to 16)
      unsigned g = ee - 1075200u;
      int o = g / 4160, k = g % 4160;
      if (o < 6) val = (k < 4096) ? k4[o * 4096 + k] : W4[o * 64 + (k - 4096)];
    }
    if (SYS) st_sys_u16(dst + e, f16bits(val));
    else dst[e] = (f16)val;
  }
}

// ============ stage 1: for point m, W-scatter in LDS + MFMA -> t row ============
template<int CI, int ITILES, int KDIM>
__device__ void stage1_body(const float* __restrict__ p, const float* __restrict__ mask,
                            const f16* __restrict__ hT_in, f16* __restrict__ tout,
                            f16* __restrict__ Wl, int m, bool local) {
  const int tid = threadIdx.x;
  const int wave = tid >> 6, lane = tid & 63;
  const int row = lane & 15, kgrp = lane >> 4;
  const int grow = wave * 16 + row;

  const float pmx = p[m * 3 + 0], pmy = p[m * 3 + 1], pmz = p[m * 3 + 2];
  f32x4 acc[ITILES];
  #pragma unroll
  for (int it = 0; it < ITILES; ++it) acc[it] = f32x4{0.f, 0.f, 0.f, 0.f};

  #pragma unroll
  for (int half = 0; half < 2; ++half) {
    __syncthreads();
    int4* w4 = (int4*)Wl;
    int4 z4 = make_int4(0, 0, 0, 0);
    #pragma unroll
    for (int i = 0; i < 8; ++i) w4[tid + i * 256] = z4;     // zero 32KB
    __syncthreads();
    {
      const int n = half * 256 + tid;
      float x = (p[n * 3 + 0] - pmx) * INV_R;
      float y = (p[n * 3 + 1] - pmy) * INV_R;
      float z = (p[n * 3 + 2] - pmz) * INV_R;
      float r2 = x * x + y * y + z * z;
      float q = 1.0f - r2;
      float att = (q > 0.0f) ? q * q * q * mask[n] : 0.0f;
      bool c1 = (x == 0.0f) && (y == 0.0f);
      bool c2 = (fabsf(y) <= fabsf(x)) && !c1;
      float r = sqrtf(x * x + y * y + 1e-9f);
      float num = c2 ? y : x;
      float den = c2 ? x : y;
      float a = atan_poly(num / den);
      float s2 = copysignf(r, x), s3 = copysignf(r, y);
      const float C4PI = 1.2732395447351628f;
      float xs = c1 ? 0.0f : (c2 ? s2 : C4PI * s3 * a);
      float ys = c1 ? 0.0f : (c2 ? C4PI * s2 * a : s3);
      float zs = z;
      int iz0, iz1, iy0, iy1, ix0, ix1;
      float wz0, wz1, wy0, wy1, wx0, wx1;
      axis_w(zs, iz0, iz1, wz0, wz1);
      axis_w(ys, iy0, iy1, wy0, wy1);
      axis_w(xs, ix0, ix1, wx0, wx1);
      wz0 *= att; wz1 *= att;
      int gz[2] = {iz0 * 16, iz1 * 16};
      int gy[2] = {iy0 * 4, iy1 * 4};
      int gx[2] = {ix0, ix1};
      float wzv[2] = {wz0, wz1}, wyv[2] = {wy0, wy1}, wxv[2] = {wx0, wx1};
      #pragma unroll
      for (int za = 0; za < 2; ++za)
        #pragma unroll
        for (int ya = 0; ya < 2; ++ya)
          #pragma unroll
          for (int xa = 0; xa < 2; ++xa) {
            float w = wzv[za] * wyv[ya] * wxv[xa];
            if (w != 0.0f) {
              int g = gz[za] + gy[ya] + gx[xa];
              Wl[g * 256 + (tid ^ ((g & 7) << 3))] = (f16)w;
            }
          }
    }
    __syncthreads();
    #pragma unroll
    for (int k0 = 0; k0 < 8; ++k0) {
      const int n0l = k0 * 32 + kgrp * 8;
      f16x8 afrag = *(f16x8*)&Wl[grow * 256 + (n0l ^ ((grow & 7) << 3))];
      f16x8 bfr[ITILES];
      #pragma unroll
      for (int it = 0; it < ITILES; ++it)
        bfr[it] = *(const f16x8*)&hT_in[(it * 16 + row) * 512 + half * 256 + n0l];
      #pragma unroll
      for (int it = 0; it < ITILES; ++it)
        acc[it] = __builtin_amdgcn_mfma_f32_16x16x32_f16(afrag, bfr[it], acc[it], 0, 0, 0);
    }
  }
  const int g4 = wave * 16 + kgrp * 4;
  #pragma unroll
  for (int it = 0; it < ITILES; ++it) {
    const int icol = it * 16 + row;
    if (icol < CI) {
      union { f16 h[4]; iv2 i; short4 s; } cv;
      #pragma unroll
      for (int r = 0; r < 4; ++r) cv.h[r] = (f16)acc[it][r];
      f16* dst = &tout[(size_t)m * KDIM + icol * 64 + g4];
      if (local) *(short4*)dst = cv.s;       // same-XCD consumer: write-back L2
      else st_sys_b64(dst, cv.i);            // cross-XCD safe
    }
  }
}

// ============ stage 2: 16m x 16o tile, 4-wave K-split, MFMA ============
template<int KDIM, bool RES, bool FINAL>
__device__ void stage2_body(const f16* __restrict__ t, const f16* __restrict__ Kf,
                            const float* __restrict__ bias, float* __restrict__ outG,
                            f16* __restrict__ hT_out, f16* __restrict__ tnext,
                            float* __restrict__ dout, float* __restrict__ red,
                            bool active, int mbase, int otile, bool local) {
  if (!active) return;
  constexpr int KSTEPS = KDIM / 32;
  int tid = threadIdx.x;
  int kpart = tid >> 6, lane = tid & 63;
  int row = lane & 15, kgrp = lane >> 4;
  int mrow = mbase + row;
  int ocol = otile * 16 + row;
  f32x4 acc = {0.f, 0.f, 0.f, 0.f};
  #pragma unroll 4
  for (int ks = kpart; ks < KSTEPS; ks += 4) {
    int k0 = ks * 32 + kgrp * 8;
    f16x8 afrag = *(const f16x8*)&t[(size_t)mrow * KDIM + k0];
    f16x8 bfrag = *(const f16x8*)&Kf[(size_t)ocol * KDIM + k0];
    acc = __builtin_amdgcn_mfma_f32_16x16x32_f16(afrag, bfrag, acc, 0, 0, 0);
  }
  if (kpart > 0) {
    #pragma unroll
    for (int r = 0; r < 4; ++r)
      red[(kpart - 1) * 256 + (kgrp * 4 + r) * 16 + row] = acc[r];
  }
  __syncthreads();
  if (kpart == 0) {
    #pragma unroll
    for (int kw = 0; kw < 3; ++kw)
      #pragma unroll
      for (int r = 0; r < 4; ++r)
        acc[r] += red[kw * 256 + (kgrp * 4 + r) * 16 + row];
    #pragma unroll
    for (int r = 0; r < 4; ++r) {
      int mm = mbase + kgrp * 4 + r;
      int oo = ocol;
      if (FINAL) {
        if (oo < 6) dout[mm * 6 + oo] = acc[r] + bias[oo];
      } else {
        float val = acc[r] + bias[oo];
        if (RES) val += outG[mm * 64 + oo];                 // same-block RMW
        outG[mm * 64 + oo] = val;
        float h = fmaxf(val, 0.0f);
        unsigned hb = f16bits(h);
        st_sys_u16(&hT_out[oo * 512 + mm], hb);             // cross-XCD: sc01 always
        f16* tp = &tnext[(size_t)mm * 4160 + 4096 + oo];
        if (local) { union { unsigned short u; f16 f; } c; c.u = (unsigned short)hb; *tp = c.f; }
        else st_sys_u16(tp, hb);
      }
    }
  }
}

// ================= cooperative mega-kernel (XCD-local pipeline + private KT) =================
__global__ __launch_bounds__(256, 2) void mega_kernel(
    const float* p, const float* v, const float* other, const float* mask,
    const float* kf, const float* Wf, const float* bf,
    const float* k1, const float* W1, const float* b1,
    const float* k2, const float* W2, const float* b2,
    const float* k3, const float* W3, const float* b3,
    const float* k4, const float* W4, const float* b4,
    float* dout, char* ws, int ktpriv) {
  __shared__ int4 blob[4096];          // 64KB: forces exactly 2 blocks/CU -> 64 blocks/XCD
  __shared__ unsigned s_rank;
  f16* Wl = (f16*)blob;
  float* red = (float*)blob;
  unsigned* bar = (unsigned*)(ws + F_BAR);
  unsigned* selfcnt = (unsigned*)(ws + F_SELF);
  unsigned* ovp = selfcnt + 8;

  // --- self-organize by PHYSICAL XCD (s_getreg HW_REG_XCC_ID, id=20) ---
  unsigned xcc;
  asm volatile("s_getreg_b32 %0, hwreg(20, 0, 32)" : "=s"(xcc));
  xcc &= 7u;
  if (threadIdx.x == 0) {
    unsigned r = atomicAdd(&selfcnt[xcc], 1u);   // device-scope
    if (r >= 64u) __hip_atomic_store(ovp, 1u, __ATOMIC_RELAXED, __HIP_MEMORY_SCOPE_AGENT);
    s_rank = r;
  }
  __syncthreads();
  unsigned rank = s_rank;

  float* B0 = (float*)(ws + F_B0);
  f16* hT0 = (f16*)(ws + F_HT);
  f16* hT1 = hT0 + 40960;
  f16* hT2 = hT0 + 81920;
  f16* hT3 = hT0 + 122880;
  f16* hT4 = hT0 + 163840;
  f16* t0 = (f16*)(ws + F_T0);
  f16* t1 = (f16*)(ws + F_T1);
  f16* t2 = (f16*)(ws + F_T2);
  f16* t3 = (f16*)(ws + F_T3);
  f16* t4 = (f16*)(ws + F_T4);
  float* outG = (float*)(ws + F_OG);

  gridbar(bar, 0);   // all self-org arrivals done -> overflow flag final
  bool local = (__hip_atomic_load(ovp, __ATOMIC_RELAXED, __HIP_MEMORY_SCOPE_AGENT) == 0u);
  bool kpriv = local && (ktpriv != 0);

  // KT copy base: copy 0 at F_K, copies 1..7 at F_KP
  f16* Kb;
  if (kpriv && xcc > 0) Kb = (f16*)(ws + F_KP + (size_t)(xcc - 1) * KT_BYTES);
  else Kb = (f16*)(ws + F_K);

  prep_shared(v, other, bf, B0, hT0, t0);
  if (kpriv) {
    // my XCD's 64 blocks build our private copy with plain write-back stores
    prep_kt<false>(kf, Wf, k1, W1, k2, W2, k3, W3, k4, W4, Kb,
                   rank * 256u + threadIdx.x, 64u * 256u);
  } else {
    // shared copy 0, sc01 (cross-XCD consumers)
    prep_kt<true>(kf, Wf, k1, W1, k2, W2, k3, W3, k4, W4, (f16*)(ws + F_K),
                  blockIdx.x * 256u + threadIdx.x, NBLK * 256u);
  }
  gridbar(bar, 1);

  int m1    = local ? (int)(xcc * 64u + rank) : (int)blockIdx.x;
  bool s2a  = local ? (rank < 16u) : (blockIdx.x < 128);
  int tix   = local ? (int)rank : (int)blockIdx.x;
  int ot    = tix & 3;
  int mbase = local ? (int)(xcc * 64u + (rank >> 2) * 16u) : ((int)(blockIdx.x >> 2) * 16);

  stage1_body<66, 5, 4320>(p, mask, hT0, t0, Wl, m1, local);
  gridbar(bar, 2);
  stage2_body<4320, false, false>(t0, Kb, B0, outG, hT1, t1, nullptr, red, s2a, mbase, ot, local);
  gridbar(bar, 3);
  stage1_body<64, 4, 4160>(p, mask, hT1, t1, Wl, m1, local);
  gridbar(bar, 4);
  stage2_body<4160, true, false>(t1, Kb + K1_OFF / 2, b1, outG, hT2, t2, nullptr, red, s2a, mbase, ot, local);
  gridbar(bar, 5);
  stage1_body<64, 4, 4160>(p, mask, hT2, t2, Wl, m1, local);
  gridbar(bar, 6);
  stage2_body<4160, true, false>(t2, Kb + K2_OFF / 2, b2, outG, hT3, t3, nullptr, red, s2a, mbase, ot, local);
  gridbar(bar, 7);
  stage1_body<64, 4, 4160>(p, mask, hT3, t3, Wl, m1, local);
  gridbar(bar, 8);
  stage2_body<4160, true, false>(t3, Kb + K3_OFF / 2, b3, outG, hT4, t4, nullptr, red, s2a, mbase, ot, local);
  gridbar(bar, 9);
  stage1_body<64, 4, 4160>(p, mask, hT4, t4, Wl, m1, local);
  gridbar(bar, 10);
  stage2_body<4160, false, true>(t4, Kb + K4_OFF / 2, b4, outG, nullptr, nullptr, dout, red, s2a, mbase, ot, local);
}

// ================= fallback: same bodies, 11 plain launches (compact layout) =================
__global__ __launch_bounds__(256) void prep_g(
    const float* v, const float* other, const float* kf, const float* Wf, const float* bf,
    const float* k1, const float* W1, const float* k2, const float* W2,
    const float* k3, const float* W3, const float* k4, const float* W4,
    f16* K0, float* B0, f16* hT0, f16* t0) {
  prep_shared(v, other, bf, B0, hT0, t0);
  prep_kt<false>(kf, Wf, k1, W1, k2, W2, k3, W3, k4, W4, K0,
                 blockIdx.x * 256u + threadIdx.x, NBLK * 256u);
}
template<int CI, int ITILES, int KDIM>
__global__ __launch_bounds__(256) void stage1_g(const float* p, const float* mask,
                                                const f16* hT_in, f16* tout) {
  __shared__ int4 blob[2048];
  stage1_body<CI, ITILES, KDIM>(p, mask, hT_in, tout, (f16*)blob, blockIdx.x, false);
}
template<int KDIM, bool RES, bool FINAL>
__global__ __launch_bounds__(256) void stage2_g(const f16* t, const f16* Kf,
                                                const float* bias, float* outG,
                                                f16* hT_out, f16* tnext, float* dout) {
  __shared__ float red[3 * 256];
  stage2_body<KDIM, RES, FINAL>(t, Kf, bias, outG, hT_out, tnext, dout, red,
                                blockIdx.x < 128, ((int)blockIdx.x >> 2) * 16,
                                (int)blockIdx.x & 3, false);
}

extern "C" void kernel_launch(void* const* d_in, const int* in_sizes, int n_in,
                              void* d_out, int out_size, void* d_ws, size_t ws_size,
                              hipStream_t stream) {
  const float* p     = (const float*)d_in[0];
  const float* v     = (const float*)d_in[1];
  const float* other = (const float*)d_in[2];
  const float* mask  = (const float*)d_in[3];
  const float* kf    = (const float*)d_in[4];
  const float* Wf    = (const float*)d_in[5];
  const float* bf    = (const float*)d_in[6];
  const float* k1    = (const float*)d_in[7];
  const float* W1    = (const float*)d_in[8];
  const float* b1    = (const float*)d_in[9];
  const float* k2    = (const float*)d_in[10];
  const float* W2    = (const float*)d_in[11];
  const float* b2    = (const float*)d_in[12];
  const float* k3    = (const float*)d_in[13];
  const float* W3    = (const float*)d_in[14];
  const float* b3    = (const float*)d_in[15];
  const float* k4    = (const float*)d_in[16];
  const float* W4    = (const float*)d_in[17];
  const float* b4    = (const float*)d_in[18];
  float* dout = (float*)d_out;
  char* ws = (char*)d_ws;
  (void)in_sizes; (void)n_in; (void)out_size;

  // ---- cooperative XCD-local path ----
  int maxb = 0;
  hipError_t e1 = hipOccupancyMaxActiveBlocksPerMultiprocessor(
      &maxb, (const void*)mega_kernel, 256, 0);
  if (e1 == hipSuccess && maxb >= 2 && ws_size >= NEED_FULL) {
    int ktpriv = (ws_size >= NEED_KTPRIV) ? 1 : 0;
    hipMemsetAsync(ws, 0, 2368, stream);   // barrier + selforg counters + ov flag
    void* args[] = {
      (void*)&p, (void*)&v, (void*)&other, (void*)&mask,
      (void*)&kf, (void*)&Wf, (void*)&bf,
      (void*)&k1, (void*)&W1, (void*)&b1,
      (void*)&k2, (void*)&W2, (void*)&b2,
      (void*)&k3, (void*)&W3, (void*)&b3,
      (void*)&k4, (void*)&W4, (void*)&b4,
      (void*)&dout, (void*)&ws, (void*)&ktpriv
    };
    hipError_t e2 = hipLaunchCooperativeKernel((const void*)mega_kernel, dim3(NBLK),
                                               dim3(256), args, 0, stream);
    if (e2 == hipSuccess) return;
  }

  // ---- fallback (compact layout): dispatch-boundary coherence ----
  f16* K0  = (f16*)(ws + C_K);
  float* B0 = (float*)(ws + C_B0);
  f16* hTA = (f16*)(ws + C_HTA);
  f16* hTB = (f16*)(ws + C_HTB);
  f16* tA  = (f16*)(ws + C_TA);
  f16* tB  = (f16*)(ws + C_TB);
  float* outG = (float*)(ws + C_OG);

  prep_g<<<NBLK, 256, 0, stream>>>(v, other, kf, Wf, bf, k1, W1, k2, W2, k3, W3, k4, W4,
                                   K0, B0, hTA, tA);
  stage1_g<66, 5, 4320><<<NBLK, 256, 0, stream>>>(p, mask, hTA, tA);
  stage2_g<4320, false, false><<<128, 256, 0, stream>>>(tA, K0, B0, outG, hTB, tB, nullptr);
  stage1_g<64, 4, 4160><<<NBLK, 256, 0, stream>>>(p, mask, hTB, tB);
  stage2_g<4160, true, false><<<128, 256, 0, stream>>>(tB, K0 + K1_OFF / 2, b1, outG, hTA, tA, nullptr);
  stage1_g<64, 4, 4160><<<NBLK, 256, 0, stream>>>(p, mask, hTA, tA);
  stage2_g<4160, true, false><<<128, 256, 0, stream>>>(tA, K0 + K2_OFF / 2, b2, outG, hTB, tB, nullptr);
  stage1_g<64, 4, 4160><<<NBLK, 256, 0, stream>>>(p, mask, hTB, tB);
  stage2_g<4160, true, false><<<128, 256, 0, stream>>>(tB, K0 + K3_OFF / 2, b3, outG, hTA, tA, nullptr);
  stage1_g<64, 4, 4160><<<NBLK, 256, 0, stream>>>(p, mask, hTA, tA);
  stage2_g<4160, false, true><<<128, 256, 0, stream>>>(tA, K0 + K4_OFF / 2, b4, outG, nullptr, nullptr, dout);
}

// Round 14
// 185.785 us; speedup vs baseline: 1.0257x; 1.0257x over previous
//
#include <hip/hip_runtime.h>

typedef _Float16 f16;
typedef _Float16 f16x8 __attribute__((ext_vector_type(8)));
typedef float f32x4 __attribute__((ext_vector_type(4)));
typedef int iv2 __attribute__((ext_vector_type(2)));

#define INV_R (1.0f / 40.0f)
#define NBLK 512

// ---- FULL layout (cooperative path), bytes ----
#define F_BAR  0u            // u32[576] barrier
#define F_SELF 2304u         // u32[8] per-XCD rank counters + u32 overflow flag
#define F_B0   2368u         // f32[64] layer-0 fused bias
#define F_K    2624u         // KT (f16, 1,141,760 elems)
#define F_HT   2286144u      // 5 x f16[80][512]
#define F_T0   2695744u      // f16[512][4320]
#define F_T1   7119424u      // f16[512][4160]
#define F_T2   11379264u
#define F_T3   15639104u
#define F_T4   19898944u
#define F_OG   24158784u     // f32[512][64] residual (block-private)
#define NEED_FULL 24289856u

#define KT_ELEMS 1141760u

// ---- COMPACT layout (fallback plain-launch path), bytes ----
#define C_B0  2304u
#define C_K   2560u
#define C_HTA 2286080u
#define C_HTB 2368000u
#define C_TA  2449920u
#define C_TB  6873600u
#define C_OG  11133440u

// K sub-offsets (bytes): K0 [64][4320], K1..K3 [64][4160], K4 [16][4160]
#define K1_OFF 552960u
#define K2_OFF 1085440u
#define K3_OFF 1617920u
#define K4_OFF 2150400u

// ---- system-scope stores ----
__device__ __forceinline__ void st_sys_u16(void* p, unsigned v) {
  asm volatile("global_store_short %0, %1, off sc0 sc1" :: "v"(p), "v"(v) : "memory");
}
__device__ __forceinline__ void st_sys_f32(float* p, float v) {
  asm volatile("global_store_dword %0, %1, off sc0 sc1" :: "v"(p), "v"(v) : "memory");
}
__device__ __forceinline__ void st_sys_b64(void* p, iv2 v) {
  asm volatile("global_store_dwordx2 %0, %1, off sc0 sc1" :: "v"(p), "v"(v) : "memory");
}
__device__ __forceinline__ unsigned f16bits(float x) {
  union { f16 h; unsigned short s; } cv; cv.h = (f16)x; return (unsigned)cv.s;
}
__device__ __forceinline__ iv2 pack4(float a, float b, float c, float d) {
  union { f16 h[4]; iv2 i; } u;
  u.h[0] = (f16)a; u.h[1] = (f16)b; u.h[2] = (f16)c; u.h[3] = (f16)d;
  return u.i;
}

// ============ fence-free hierarchical grid barrier (r11, backoff) ============
__device__ __forceinline__ unsigned bar_ld(unsigned* p) {
  return __hip_atomic_load(p, __ATOMIC_RELAXED, __HIP_MEMORY_SCOPE_AGENT);
}
__device__ void gridbar(unsigned* bar, int phase) {
  asm volatile("s_waitcnt vmcnt(0)" ::: "memory");
  __syncthreads();
  if (threadIdx.x == 0) {
    int bid = blockIdx.x;
    int cls = bid & 7;
    unsigned* xcnt = bar + cls * 32 + phase;
    unsigned* xrel = bar + 256 + cls * 32 + phase;
    unsigned* gcnt = bar + 512 + phase;
    unsigned* grel = bar + 544 + phase;
    __hip_atomic_fetch_add(xcnt, 1u, __ATOMIC_RELAXED, __HIP_MEMORY_SCOPE_AGENT);
    if (bid < 8) {
      while (bar_ld(xcnt) < (NBLK / 8)) __builtin_amdgcn_s_sleep(2);
      __hip_atomic_fetch_add(gcnt, 1u, __ATOMIC_RELAXED, __HIP_MEMORY_SCOPE_AGENT);
      if (bid == 0) {
        while (bar_ld(gcnt) < 8u) __builtin_amdgcn_s_sleep(2);
        __hip_atomic_store(grel, 1u, __ATOMIC_RELAXED, __HIP_MEMORY_SCOPE_AGENT);
      } else {
        while (bar_ld(grel) == 0u) __builtin_amdgcn_s_sleep(4);
      }
      __hip_atomic_store(xrel, 1u, __ATOMIC_RELAXED, __HIP_MEMORY_SCOPE_AGENT);
    } else {
      while (bar_ld(xrel) == 0u) __builtin_amdgcn_s_sleep(64);
    }
    asm volatile("" ::: "memory");
  }
  __syncthreads();
}

// ================= math helpers =================
__device__ __forceinline__ float feats0_val(int ch, int n, const float* v, const float* other) {
  if (ch == 0) return 1.0f;
  if (ch < 4) return v[n * 3 + (ch - 1)];
  return other[n * 62 + (ch - 4)];
}
__device__ __forceinline__ float atan_poly(float t) {
  float t2 = t * t;
  float p = -0.0117212f;
  p = p * t2 + 0.05265332f;
  p = p * t2 - 0.11643287f;
  p = p * t2 + 0.19354346f;
  p = p * t2 - 0.33262347f;
  p = p * t2 + 0.99997726f;
  return t * p;
}
__device__ __forceinline__ void axis_w(float g, int& i0c, int& i1c, float& w0, float& w1) {
  float c = 2.0f * g + 1.5f;
  float fl = floorf(c);
  float f = c - fl;
  int i0 = (int)fl;
  w0 = (i0 >= 0 && i0 <= 3) ? (1.0f - f) : 0.0f;
  w1 = (i0 >= -1 && i0 <= 2) ? f : 0.0f;
  i0c = min(max(i0, 0), 3);
  i1c = min(max(i0 + 1, 0), 3);
}

// KT element value (packed [o][KDIM] rows for all 5 layers, f16)
__device__ float kt_val(unsigned ee,
                        const float* kf, const float* Wf,
                        const float* k1, const float* W1,
                        const float* k2, const float* W2,
                        const float* k3, const float* W3,
                        const float* k4, const float* W4) {
  if (ee < 276480u) {                       // K0: rows 0..31 conv, rows 32..63 dense
    int o = ee / 4320, k = ee % 4320;
    if (o < 32) return (k < 4224) ? kf[o * 4224 + k] : 0.0f;
    return (k >= 4224 && k < 4290) ? Wf[(o - 32) * 66 + (k - 4224)] : 0.0f;
  }
  if (ee < 1075200u) {                      // K1..K3: conv 4096 | dense 64
    unsigned f = ee - 276480u;
    int which = f / 266240, g = f % 266240;
    const float* kk = which == 0 ? k1 : (which == 1 ? k2 : k3);
    const float* WW = which == 0 ? W1 : (which == 1 ? W2 : W3);
    int o = g / 4160, k = g % 4160;
    return (k < 4096) ? kk[o * 4096 + k] : WW[o * 64 + (k - 4096)];
  }
  unsigned g = ee - 1075200u;               // K4 (6 real rows, padded to 16)
  int o = g / 4160, k = g % 4160;
  if (o < 6) return (k < 4096) ? k4[o * 4096 + k] : W4[o * 64 + (k - 4096)];
  return 0.0f;
}

// ============ prep: hT0, t0 dense tail, B0, KT — batched b64 sc01 stores ============
#define PREP_CHUNKS (10240u + 12288u + 64u + KT_ELEMS / 4u)
__device__ void prep_body(const float* __restrict__ v, const float* __restrict__ other,
                          const float* __restrict__ bf,
                          const float* __restrict__ kf, const float* __restrict__ Wf,
                          const float* __restrict__ k1, const float* __restrict__ W1,
                          const float* __restrict__ k2, const float* __restrict__ W2,
                          const float* __restrict__ k3, const float* __restrict__ W3,
                          const float* __restrict__ k4, const float* __restrict__ W4,
                          f16* __restrict__ KT, float* __restrict__ B0,
                          f16* __restrict__ hT0, f16* __restrict__ t0,
                          unsigned start, unsigned stride) {
  for (unsigned c = start; c < PREP_CHUNKS; c += stride) {
    unsigned e = c;
    if (e < 10240u) {                        // hT0: 4 consecutive n, same row i
      unsigned b = e * 4u;
      int i = b >> 9, n = b & 511;
      float v0 = (i < 66) ? feats0_val(i, n + 0, v, other) : 0.0f;
      float v1 = (i < 66) ? feats0_val(i, n + 1, v, other) : 0.0f;
      float v2 = (i < 66) ? feats0_val(i, n + 2, v, other) : 0.0f;
      float v3 = (i < 66) ? feats0_val(i, n + 3, v, other) : 0.0f;
      st_sys_b64(hT0 + b, pack4(v0, v1, v2, v3));
      continue;
    }
    e -= 10240u;
    if (e < 12288u) {                        // t0 dense tail: 4 consecutive j, same m
      unsigned b = e * 4u;
      int m = b / 96, j = b % 96;
      float v0 = (j + 0 < 66) ? feats0_val(j + 0, m, v, other) : 0.0f;
      float v1 = (j + 1 < 66) ? feats0_val(j + 1, m, v, other) : 0.0f;
      float v2 = (j + 2 < 66) ? feats0_val(j + 2, m, v, other) : 0.0f;
      float v3 = (j + 3 < 66) ? feats0_val(j + 3, m, v, other) : 0.0f;
      st_sys_b64(t0 + (size_t)m * 4320 + 4224 + j, pack4(v0, v1, v2, v3));
      continue;
    }
    e -= 12288u;
    if (e < 64u) {
      st_sys_f32(&B0[e], (e < 32u) ? 0.0f : bf[e - 32u]);
      continue;
    }
    e -= 64u;
    {                                        // KT: 4 consecutive elems
      unsigned b = e * 4u;
      float v0 = kt_val(b + 0, kf, Wf, k1, W1, k2, W2, k3, W3, k4, W4);
      float v1 = kt_val(b + 1, kf, Wf, k1, W1, k2, W2, k3, W3, k4, W4);
      float v2 = kt_val(b + 2, kf, Wf, k1, W1, k2, W2, k3, W3, k4, W4);
      float v3 = kt_val(b + 3, kf, Wf, k1, W1, k2, W2, k3, W3, k4, W4);
      st_sys_b64(KT + b, pack4(v0, v1, v2, v3));
    }
  }
}

// ============ stage 1: for point m, W-scatter in LDS + MFMA -> t row ============
template<int CI, int ITILES, int KDIM>
__device__ void stage1_body(const float* __restrict__ p, const float* __restrict__ mask,
                            const f16* __restrict__ hT_in, f16* __restrict__ tout,
                            f16* __restrict__ Wl, int m, bool local) {
  const int tid = threadIdx.x;
  const int wave = tid >> 6, lane = tid & 63;
  const int row = lane & 15, kgrp = lane >> 4;
  const int grow = wave * 16 + row;

  const float pmx = p[m * 3 + 0], pmy = p[m * 3 + 1], pmz = p[m * 3 + 2];
  f32x4 acc[ITILES];
  #pragma unroll
  for (int it = 0; it < ITILES; ++it) acc[it] = f32x4{0.f, 0.f, 0.f, 0.f};

  #pragma unroll
  for (int half = 0; half < 2; ++half) {
    __syncthreads();
    int4* w4 = (int4*)Wl;
    int4 z4 = make_int4(0, 0, 0, 0);
    #pragma unroll
    for (int i = 0; i < 8; ++i) w4[tid + i * 256] = z4;     // zero 32KB
    __syncthreads();
    {
      const int n = half * 256 + tid;
      float x = (p[n * 3 + 0] - pmx) * INV_R;
      float y = (p[n * 3 + 1] - pmy) * INV_R;
      float z = (p[n * 3 + 2] - pmz) * INV_R;
      float r2 = x * x + y * y + z * z;
      float q = 1.0f - r2;
      float att = (q > 0.0f) ? q * q * q * mask[n] : 0.0f;
      bool c1 = (x == 0.0f) && (y == 0.0f);
      bool c2 = (fabsf(y) <= fabsf(x)) && !c1;
      float r = sqrtf(x * x + y * y + 1e-9f);
      float num = c2 ? y : x;
      float den = c2 ? x : y;
      float a = atan_poly(num / den);
      float s2 = copysignf(r, x), s3 = copysignf(r, y);
      const float C4PI = 1.2732395447351628f;
      float xs = c1 ? 0.0f : (c2 ? s2 : C4PI * s3 * a);
      float ys = c1 ? 0.0f : (c2 ? C4PI * s2 * a : s3);
      float zs = z;
      int iz0, iz1, iy0, iy1, ix0, ix1;
      float wz0, wz1, wy0, wy1, wx0, wx1;
      axis_w(zs, iz0, iz1, wz0, wz1);
      axis_w(ys, iy0, iy1, wy0, wy1);
      axis_w(xs, ix0, ix1, wx0, wx1);
      wz0 *= att; wz1 *= att;
      int gz[2] = {iz0 * 16, iz1 * 16};
      int gy[2] = {iy0 * 4, iy1 * 4};
      int gx[2] = {ix0, ix1};
      float wzv[2] = {wz0, wz1}, wyv[2] = {wy0, wy1}, wxv[2] = {wx0, wx1};
      #pragma unroll
      for (int za = 0; za < 2; ++za)
        #pragma unroll
        for (int ya = 0; ya < 2; ++ya)
          #pragma unroll
          for (int xa = 0; xa < 2; ++xa) {
            float w = wzv[za] * wyv[ya] * wxv[xa];
            if (w != 0.0f) {
              int g = gz[za] + gy[ya] + gx[xa];
              Wl[g * 256 + (tid ^ ((g & 7) << 3))] = (f16)w;
            }
          }
    }
    __syncthreads();
    #pragma unroll
    for (int k0 = 0; k0 < 8; ++k0) {
      const int n0l = k0 * 32 + kgrp * 8;
      f16x8 afrag = *(f16x8*)&Wl[grow * 256 + (n0l ^ ((grow & 7) << 3))];
      f16x8 bfr[ITILES];
      #pragma unroll
      for (int it = 0; it < ITILES; ++it)
        bfr[it] = *(const f16x8*)&hT_in[(it * 16 + row) * 512 + half * 256 + n0l];
      #pragma unroll
      for (int it = 0; it < ITILES; ++it)
        acc[it] = __builtin_amdgcn_mfma_f32_16x16x32_f16(afrag, bfr[it], acc[it], 0, 0, 0);
    }
  }
  const int g4 = wave * 16 + kgrp * 4;
  #pragma unroll
  for (int it = 0; it < ITILES; ++it) {
    const int icol = it * 16 + row;
    if (icol < CI) {
      union { f16 h[4]; iv2 i; short4 s; } cv;
      #pragma unroll
      for (int r = 0; r < 4; ++r) cv.h[r] = (f16)acc[it][r];
      f16* dst = &tout[(size_t)m * KDIM + icol * 64 + g4];
      if (local) *(short4*)dst = cv.s;       // same-XCD consumer: write-back L2
      else st_sys_b64(dst, cv.i);            // cross-XCD safe
    }
  }
}

// ============ stage 2: 16m x 16o tile, 4-wave K-split, MFMA; batched-b64 epilogue ============
template<int KDIM, bool RES, bool FINAL>
__device__ void stage2_body(const f16* __restrict__ t, const f16* __restrict__ Kf,
                            const float* __restrict__ bias, float* __restrict__ outG,
                            f16* __restrict__ hT_out, f16* __restrict__ tnext,
                            float* __restrict__ dout, float* __restrict__ red,
                            bool active, int mbase, int otile, bool local) {
  if (!active) return;
  constexpr int KSTEPS = KDIM / 32;
  int tid = threadIdx.x;
  int kpart = tid >> 6, lane = tid & 63;
  int row = lane & 15, kgrp = lane >> 4;
  int mrow = mbase + row;
  int ocol = otile * 16 + row;
  f32x4 acc = {0.f, 0.f, 0.f, 0.f};
  #pragma unroll 4
  for (int ks = kpart; ks < KSTEPS; ks += 4) {
    int k0 = ks * 32 + kgrp * 8;
    f16x8 afrag = *(const f16x8*)&t[(size_t)mrow * KDIM + k0];
    f16x8 bfrag = *(const f16x8*)&Kf[(size_t)ocol * KDIM + k0];
    acc = __builtin_amdgcn_mfma_f32_16x16x32_f16(afrag, bfrag, acc, 0, 0, 0);
  }
  if (kpart > 0) {
    #pragma unroll
    for (int r = 0; r < 4; ++r)
      red[(kpart - 1) * 256 + (kgrp * 4 + r) * 16 + row] = acc[r];
  }
  __syncthreads();
  if (kpart == 0) {
    #pragma unroll
    for (int kw = 0; kw < 3; ++kw)
      #pragma unroll
      for (int r = 0; r < 4; ++r)
        acc[r] += red[kw * 256 + (kgrp * 4 + r) * 16 + row];
    if (FINAL) {
      #pragma unroll
      for (int r = 0; r < 4; ++r) {
        int mm = mbase + kgrp * 4 + r;
        if (ocol < 6) dout[mm * 6 + ocol] = acc[r] + bias[ocol];
      }
    } else {
      float h[4];
      #pragma unroll
      for (int r = 0; r < 4; ++r) {
        int mm = mbase + kgrp * 4 + r;
        float val = acc[r] + bias[ocol];
        if (RES) val += outG[mm * 64 + ocol];               // same-block RMW
        outG[mm * 64 + ocol] = val;
        h[r] = fmaxf(val, 0.0f);
      }
      // hT: 4 m-consecutive values, ONE b64 sc01 store (adjacent lanes merge to 32B)
      st_sys_b64(&hT_out[ocol * 512 + mbase + kgrp * 4], pack4(h[0], h[1], h[2], h[3]));
      // tnext dense tail (m-major): plain write-back in local mode
      #pragma unroll
      for (int r = 0; r < 4; ++r) {
        int mm = mbase + kgrp * 4 + r;
        f16* tp = &tnext[(size_t)mm * 4160 + 4096 + ocol];
        if (local) *tp = (f16)h[r];
        else st_sys_u16(tp, f16bits(h[r]));
      }
    }
  }
}

// ================= cooperative mega-kernel (XCD-local t, batched sc01) =================
__global__ __launch_bounds__(256, 2) void mega_kernel(
    const float* p, const float* v, const float* other, const float* mask,
    const float* kf, const float* Wf, const float* bf,
    const float* k1, const float* W1, const float* b1,
    const float* k2, const float* W2, const float* b2,
    const float* k3, const float* W3, const float* b3,
    const float* k4, const float* W4, const float* b4,
    float* dout, char* ws) {
  __shared__ int4 blob[4096];          // 64KB: forces exactly 2 blocks/CU -> 64 blocks/XCD
  __shared__ unsigned s_rank;
  f16* Wl = (f16*)blob;
  float* red = (float*)blob;
  unsigned* bar = (unsigned*)(ws + F_BAR);
  unsigned* selfcnt = (unsigned*)(ws + F_SELF);
  unsigned* ovp = selfcnt + 8;

  // --- self-organize by PHYSICAL XCD ---
  unsigned xcc;
  asm volatile("s_getreg_b32 %0, hwreg(20, 0, 32)" : "=s"(xcc));
  xcc &= 7u;
  if (threadIdx.x == 0) {
    unsigned r = atomicAdd(&selfcnt[xcc], 1u);
    if (r >= 64u) __hip_atomic_store(ovp, 1u, __ATOMIC_RELAXED, __HIP_MEMORY_SCOPE_AGENT);
    s_rank = r;
  }
  __syncthreads();
  unsigned rank = s_rank;

  f16* KT  = (f16*)(ws + F_K);
  float* B0 = (float*)(ws + F_B0);
  f16* hT0 = (f16*)(ws + F_HT);
  f16* hT1 = hT0 + 40960;
  f16* hT2 = hT0 + 81920;
  f16* hT3 = hT0 + 122880;
  f16* hT4 = hT0 + 163840;
  f16* t0 = (f16*)(ws + F_T0);
  f16* t1 = (f16*)(ws + F_T1);
  f16* t2 = (f16*)(ws + F_T2);
  f16* t3 = (f16*)(ws + F_T3);
  f16* t4 = (f16*)(ws + F_T4);
  float* outG = (float*)(ws + F_OG);

  prep_body(v, other, bf, kf, Wf, k1, W1, k2, W2, k3, W3, k4, W4,
            KT, B0, hT0, t0, blockIdx.x * 256u + threadIdx.x, NBLK * 256u);
  gridbar(bar, 0);
  bool local = (__hip_atomic_load(ovp, __ATOMIC_RELAXED, __HIP_MEMORY_SCOPE_AGENT) == 0u);

  int m1    = local ? (int)(xcc * 64u + rank) : (int)blockIdx.x;
  bool s2a  = local ? (rank < 16u) : (blockIdx.x < 128);
  int tix   = local ? (int)rank : (int)blockIdx.x;
  int ot    = tix & 3;
  int mbase = local ? (int)(xcc * 64u + (rank >> 2) * 16u) : ((int)(blockIdx.x >> 2) * 16);

  stage1_body<66, 5, 4320>(p, mask, hT0, t0, Wl, m1, local);
  gridbar(bar, 1);
  stage2_body<4320, false, false>(t0, KT, B0, outG, hT1, t1, nullptr, red, s2a, mbase, ot, local);
  gridbar(bar, 2);
  stage1_body<64, 4, 4160>(p, mask, hT1, t1, Wl, m1, local);
  gridbar(bar, 3);
  stage2_body<4160, true, false>(t1, KT + K1_OFF / 2, b1, outG, hT2, t2, nullptr, red, s2a, mbase, ot, local);
  gridbar(bar, 4);
  stage1_body<64, 4, 4160>(p, mask, hT2, t2, Wl, m1, local);
  gridbar(bar, 5);
  stage2_body<4160, true, false>(t2, KT + K2_OFF / 2, b2, outG, hT3, t3, nullptr, red, s2a, mbase, ot, local);
  gridbar(bar, 6);
  stage1_body<64, 4, 4160>(p, mask, hT3, t3, Wl, m1, local);
  gridbar(bar, 7);
  stage2_body<4160, true, false>(t3, KT + K3_OFF / 2, b3, outG, hT4, t4, nullptr, red, s2a, mbase, ot, local);
  gridbar(bar, 8);
  stage1_body<64, 4, 4160>(p, mask, hT4, t4, Wl, m1, local);
  gridbar(bar, 9);
  stage2_body<4160, false, true>(t4, KT + K4_OFF / 2, b4, outG, nullptr, nullptr, dout, red, s2a, mbase, ot, local);
}

// ================= fallback: same bodies, 11 plain launches (compact layout) =================
__global__ __launch_bounds__(256) void prep_g(
    const float* v, const float* other, const float* bf,
    const float* kf, const float* Wf,
    const float* k1, const float* W1, const float* k2, const float* W2,
    const float* k3, const float* W3, const float* k4, const float* W4,
    f16* KT, float* B0, f16* hT0, f16* t0) {
  prep_body(v, other, bf, kf, Wf, k1, W1, k2, W2, k3, W3, k4, W4,
            KT, B0, hT0, t0, blockIdx.x * 256u + threadIdx.x, NBLK * 256u);
}
template<int CI, int ITILES, int KDIM>
__global__ __launch_bounds__(256) void stage1_g(const float* p, const float* mask,
                                                const f16* hT_in, f16* tout) {
  __shared__ int4 blob[2048];
  stage1_body<CI, ITILES, KDIM>(p, mask, hT_in, tout, (f16*)blob, blockIdx.x, false);
}
template<int KDIM, bool RES, bool FINAL>
__global__ __launch_bounds__(256) void stage2_g(const f16* t, const f16* Kf,
                                                const float* bias, float* outG,
                                                f16* hT_out, f16* tnext, float* dout) {
  __shared__ float red[3 * 256];
  stage2_body<KDIM, RES, FINAL>(t, Kf, bias, outG, hT_out, tnext, dout, red,
                                blockIdx.x < 128, ((int)blockIdx.x >> 2) * 16,
                                (int)blockIdx.x & 3, false);
}

extern "C" void kernel_launch(void* const* d_in, const int* in_sizes, int n_in,
                              void* d_out, int out_size, void* d_ws, size_t ws_size,
                              hipStream_t stream) {
  const float* p     = (const float*)d_in[0];
  const float* v     = (const float*)d_in[1];
  const float* other = (const float*)d_in[2];
  const float* mask  = (const float*)d_in[3];
  const float* kf    = (const float*)d_in[4];
  const float* Wf    = (const float*)d_in[5];
  const float* bf    = (const float*)d_in[6];
  const float* k1    = (const float*)d_in[7];
  const float* W1    = (const float*)d_in[8];
  const float* b1    = (const float*)d_in[9];
  const float* k2    = (const float*)d_in[10];
  const float* W2    = (const float*)d_in[11];
  const float* b2    = (const float*)d_in[12];
  const float* k3    = (const float*)d_in[13];
  const float* W3    = (const float*)d_in[14];
  const float* b3    = (const float*)d_in[15];
  const float* k4    = (const float*)d_in[16];
  const float* W4    = (const float*)d_in[17];
  const float* b4    = (const float*)d_in[18];
  float* dout = (float*)d_out;
  char* ws = (char*)d_ws;
  (void)in_sizes; (void)n_in; (void)out_size;

  // ---- cooperative XCD-local path ----
  int maxb = 0;
  hipError_t e1 = hipOccupancyMaxActiveBlocksPerMultiprocessor(
      &maxb, (const void*)mega_kernel, 256, 0);
  if (e1 == hipSuccess && maxb >= 2 && ws_size >= NEED_FULL) {
    hipMemsetAsync(ws, 0, 2368, stream);   // barrier + selforg counters + ov flag
    void* args[] = {
      (void*)&p, (void*)&v, (void*)&other, (void*)&mask,
      (void*)&kf, (void*)&Wf, (void*)&bf,
      (void*)&k1, (void*)&W1, (void*)&b1,
      (void*)&k2, (void*)&W2, (void*)&b2,
      (void*)&k3, (void*)&W3, (void*)&b3,
      (void*)&k4, (void*)&W4, (void*)&b4,
      (void*)&dout, (void*)&ws
    };
    hipError_t e2 = hipLaunchCooperativeKernel((const void*)mega_kernel, dim3(NBLK),
                                               dim3(256), args, 0, stream);
    if (e2 == hipSuccess) return;
  }

  // ---- fallback (compact layout): dispatch-boundary coherence ----
  f16* KT  = (f16*)(ws + C_K);
  float* B0 = (float*)(ws + C_B0);
  f16* hTA = (f16*)(ws + C_HTA);
  f16* hTB = (f16*)(ws + C_HTB);
  f16* tA  = (f16*)(ws + C_TA);
  f16* tB  = (f16*)(ws + C_TB);
  float* outG = (float*)(ws + C_OG);

  prep_g<<<NBLK, 256, 0, stream>>>(v, other, bf, kf, Wf, k1, W1, k2, W2, k3, W3, k4, W4,
                                   KT, B0, hTA, tA);
  stage1_g<66, 5, 4320><<<NBLK, 256, 0, stream>>>(p, mask, hTA, tA);
  stage2_g<4320, false, false><<<128, 256, 0, stream>>>(tA, KT, B0, outG, hTB, tB, nullptr);
  stage1_g<64, 4, 4160><<<NBLK, 256, 0, stream>>>(p, mask, hTB, tB);
  stage2_g<4160, true, false><<<128, 256, 0, stream>>>(tB, KT + K1_OFF / 2, b1, outG, hTA, tA, nullptr);
  stage1_g<64, 4, 4160><<<NBLK, 256, 0, stream>>>(p, mask, hTA, tA);
  stage2_g<4160, true, false><<<128, 256, 0, stream>>>(tA, KT + K2_OFF / 2, b2, outG, hTB, tB, nullptr);
  stage1_g<64, 4, 4160><<<NBLK, 256, 0, stream>>>(p, mask, hTB, tB);
  stage2_g<4160, true, false><<<128, 256, 0, stream>>>(tB, KT + K3_OFF / 2, b3, outG, hTA, tA, nullptr);
  stage1_g<64, 4, 4160><<<NBLK, 256, 0, stream>>>(p, mask, hTA, tA);
  stage2_g<4160, false, true><<<128, 256, 0, stream>>>(tA, KT + K4_OFF / 2, b4, outG, nullptr, nullptr, dout);
}